// Round 5
// baseline (646.826 us; speedup 1.0000x reference)
//
#include <hip/hip_runtime.h>

#define IN_F 128
#define EF 16

// bf16 helpers: pack is RNE; unpack low/high halves of a uint holding 2 bf16
__device__ __forceinline__ unsigned short f2b(float f) {
    unsigned b = __float_as_uint(f);
    b += 0x7fffu + ((b >> 16) & 1u);
    return (unsigned short)(b >> 16);
}
__device__ __forceinline__ float blo(unsigned u) { return __uint_as_float(u << 16); }
__device__ __forceinline__ float bhi(unsigned u) { return __uint_as_float(u & 0xffff0000u); }

// ============================ CSR-build path ================================

__global__ __launch_bounds__(256) void hist_kernel(
    const int* __restrict__ ei, int* __restrict__ counts, int E)
{
    int e = blockIdx.x * 256 + threadIdx.x;
    if (e >= E) return;
    atomicAdd(&counts[ei[E + e]], 1);
}

__global__ __launch_bounds__(256) void scan_blocks_kernel(
    const int* __restrict__ in, int* __restrict__ out,
    int* __restrict__ partials, int n)
{
    __shared__ int sdata[256];
    const int t = threadIdx.x;
    const int idx0 = blockIdx.x * 1024 + t * 4;
    int v[4];
    #pragma unroll
    for (int i = 0; i < 4; i++) { int idx = idx0 + i; v[i] = (idx < n) ? in[idx] : 0; }
    int s = v[0] + v[1] + v[2] + v[3];
    sdata[t] = s;
    __syncthreads();
    for (int off = 1; off < 256; off <<= 1) {
        int x = (t >= off) ? sdata[t - off] : 0;
        __syncthreads();
        sdata[t] += x;
        __syncthreads();
    }
    if (t == 255) partials[blockIdx.x] = sdata[255];
    int run = (t > 0) ? sdata[t - 1] : 0;
    #pragma unroll
    for (int i = 0; i < 4; i++) {
        int idx = idx0 + i;
        if (idx < n) out[idx] = run;
        run += v[i];
    }
}

__global__ void scan_partials_kernel(int* partials, int B)
{
    __shared__ int sdata[1024];
    const int t = threadIdx.x;
    sdata[t] = (t < B) ? partials[t] : 0;
    __syncthreads();
    for (int off = 1; off < 1024; off <<= 1) {
        int x = (t >= off) ? sdata[t - off] : 0;
        __syncthreads();
        sdata[t] += x;
        __syncthreads();
    }
    if (t < B) partials[t] = (t > 0) ? sdata[t - 1] : 0;
}

__global__ __launch_bounds__(256) void scan_add_kernel(
    int* __restrict__ out, const int* __restrict__ partials, int n)
{
    int idx = blockIdx.x * 256 + threadIdx.x;
    if (idx < n) out[idx] += partials[idx >> 10];
}

__global__ __launch_bounds__(256) void build_kernel(
    const int* __restrict__ ei, int2* __restrict__ sorted,
    const int* __restrict__ offsets, int* __restrict__ cursor, int E)
{
    int e = blockIdx.x * 256 + threadIdx.x;
    if (e >= E) return;
    int src = ei[e];
    int dst = ei[E + e];
    int pos = offsets[dst] + atomicAdd(&cursor[dst], 1);
    sorted[pos] = make_int2(src, e);
}

// cast H (fp32) -> Hb (bf16, RNE), vectorized 4-wide
__global__ __launch_bounds__(256) void h2b_kernel(
    const float* __restrict__ H, unsigned short* __restrict__ Hb, int n4)
{
    int i = blockIdx.x * 256 + threadIdx.x;
    if (i >= n4) return;
    float4 v = ((const float4*)H)[i];
    ushort4 r;
    r.x = f2b(v.x); r.y = f2b(v.y); r.z = f2b(v.z); r.w = f2b(v.w);
    ((ushort4*)Hb)[i] = r;
}

// gather (bf16 H): one wave per node; half-waves (32 lanes) each own one edge
// slot; lane covers feats [4*l32, 4*l32+3] via one 8B uint2 load (4 bf16).
// Unroll x4 -> 8 edges in flight per wave. Halves combined with shfl_xor(32).
__global__ __launch_bounds__(256) void gather_bf16_kernel(
    const unsigned short* __restrict__ Hb,
    const float* __restrict__ EA,
    const int2* __restrict__ sorted,
    const int* __restrict__ offsets,
    float* __restrict__ agg,            // [N,128] = d_out
    float* __restrict__ aggE,           // [N,16]
    float* __restrict__ degf,           // [N]
    int N)
{
    int n = blockIdx.x * 4 + (threadIdx.x >> 6);
    if (n >= N) return;
    int lane = threadIdx.x & 63;
    int half = lane >> 5;
    int l32  = lane & 31;
    int s = offsets[n];
    int e_end = offsets[n + 1];
    float a0 = 0.f, a1 = 0.f, a2 = 0.f, a3 = 0.f, accE = 0.f;
    int i = s + half;
    for (; i + 6 < e_end; i += 8) {
        int2 s0 = sorted[i];
        int2 s1 = sorted[i + 2];
        int2 s2 = sorted[i + 4];
        int2 s3 = sorted[i + 6];
        uint2 u0 = *(const uint2*)(Hb + (long long)s0.x * IN_F + l32 * 4);
        uint2 u1 = *(const uint2*)(Hb + (long long)s1.x * IN_F + l32 * 4);
        uint2 u2 = *(const uint2*)(Hb + (long long)s2.x * IN_F + l32 * 4);
        uint2 u3 = *(const uint2*)(Hb + (long long)s3.x * IN_F + l32 * 4);
        float e0 = 0.f, e1 = 0.f, e2 = 0.f, e3 = 0.f;
        if (l32 < EF) {
            e0 = EA[(long long)s0.y * EF + l32];
            e1 = EA[(long long)s1.y * EF + l32];
            e2 = EA[(long long)s2.y * EF + l32];
            e3 = EA[(long long)s3.y * EF + l32];
        }
        a0 += (blo(u0.x) + blo(u1.x)) + (blo(u2.x) + blo(u3.x));
        a1 += (bhi(u0.x) + bhi(u1.x)) + (bhi(u2.x) + bhi(u3.x));
        a2 += (blo(u0.y) + blo(u1.y)) + (blo(u2.y) + blo(u3.y));
        a3 += (bhi(u0.y) + bhi(u1.y)) + (bhi(u2.y) + bhi(u3.y));
        accE += (e0 + e1) + (e2 + e3);
    }
    for (; i < e_end; i += 2) {
        int2 se = sorted[i];
        uint2 u = *(const uint2*)(Hb + (long long)se.x * IN_F + l32 * 4);
        a0 += blo(u.x); a1 += bhi(u.x); a2 += blo(u.y); a3 += bhi(u.y);
        if (l32 < EF) accE += EA[(long long)se.y * EF + l32];
    }
    a0 += __shfl_xor(a0, 32, 64);
    a1 += __shfl_xor(a1, 32, 64);
    a2 += __shfl_xor(a2, 32, 64);
    a3 += __shfl_xor(a3, 32, 64);
    accE += __shfl_xor(accE, 32, 64);
    if (half == 0) {
        *(float4*)(agg + (long long)n * IN_F + l32 * 4) = make_float4(a0, a1, a2, a3);
        if (l32 < EF) aggE[n * EF + l32] = accE;
        if (l32 == 0) degf[n] = (float)(e_end - s);
    }
}

// gather (fp32 H) fallback when ws can't hold Hb: same structure, float4 loads
__global__ __launch_bounds__(256) void gather_f32_kernel(
    const float* __restrict__ H,
    const float* __restrict__ EA,
    const int2* __restrict__ sorted,
    const int* __restrict__ offsets,
    float* __restrict__ agg,
    float* __restrict__ aggE,
    float* __restrict__ degf,
    int N)
{
    int n = blockIdx.x * 4 + (threadIdx.x >> 6);
    if (n >= N) return;
    int lane = threadIdx.x & 63;
    int half = lane >> 5;
    int l32  = lane & 31;
    int s = offsets[n];
    int e_end = offsets[n + 1];
    float4 acc = make_float4(0.f, 0.f, 0.f, 0.f);
    float accE = 0.f;
    int i = s + half;
    for (; i + 6 < e_end; i += 8) {
        int2 s0 = sorted[i];
        int2 s1 = sorted[i + 2];
        int2 s2 = sorted[i + 4];
        int2 s3 = sorted[i + 6];
        float4 v0 = *(const float4*)(H + (long long)s0.x * IN_F + l32 * 4);
        float4 v1 = *(const float4*)(H + (long long)s1.x * IN_F + l32 * 4);
        float4 v2 = *(const float4*)(H + (long long)s2.x * IN_F + l32 * 4);
        float4 v3 = *(const float4*)(H + (long long)s3.x * IN_F + l32 * 4);
        float e0 = 0.f, e1 = 0.f, e2 = 0.f, e3 = 0.f;
        if (l32 < EF) {
            e0 = EA[(long long)s0.y * EF + l32];
            e1 = EA[(long long)s1.y * EF + l32];
            e2 = EA[(long long)s2.y * EF + l32];
            e3 = EA[(long long)s3.y * EF + l32];
        }
        acc.x += (v0.x + v1.x) + (v2.x + v3.x);
        acc.y += (v0.y + v1.y) + (v2.y + v3.y);
        acc.z += (v0.z + v1.z) + (v2.z + v3.z);
        acc.w += (v0.w + v1.w) + (v2.w + v3.w);
        accE  += (e0 + e1) + (e2 + e3);
    }
    for (; i < e_end; i += 2) {
        int2 se = sorted[i];
        float4 v = *(const float4*)(H + (long long)se.x * IN_F + l32 * 4);
        acc.x += v.x; acc.y += v.y; acc.z += v.z; acc.w += v.w;
        if (l32 < EF) accE += EA[(long long)se.y * EF + l32];
    }
    acc.x += __shfl_xor(acc.x, 32, 64);
    acc.y += __shfl_xor(acc.y, 32, 64);
    acc.z += __shfl_xor(acc.z, 32, 64);
    acc.w += __shfl_xor(acc.w, 32, 64);
    accE  += __shfl_xor(accE, 32, 64);
    if (half == 0) {
        *(float4*)(agg + (long long)n * IN_F + l32 * 4) = acc;
        if (l32 < EF) aggE[n * EF + l32] = accE;
        if (l32 == 0) degf[n] = (float)(e_end - s);
    }
}

// ======================= fallback: atomic scatter ===========================
__global__ __launch_bounds__(256) void edge_scatter_kernel(
    const float* __restrict__ H,
    const int* __restrict__ ei,
    const float* __restrict__ EA,
    float* __restrict__ agg,
    float* __restrict__ aggE,
    float* __restrict__ deg,
    int E)
{
    long long gid = (long long)blockIdx.x * 256 + threadIdx.x;
    int e = (int)(gid >> 7);
    if (e >= E) return;
    int f = (int)(gid & 127);
    int src = ei[e];
    int dst = ei[E + e];
    float m = H[(long long)src * IN_F + f];
    atomicAdd(&agg[(long long)dst * IN_F + f], m);
    if (f < EF) atomicAdd(&aggE[dst * EF + f], EA[e * EF + f]);
    if (f == 0) atomicAdd(&deg[dst], 1.0f);
}

// ============================== node MLP ====================================
// 64-row tile, 256 threads, 32 outputs/thread (cols c4..c4+3, rows r0+8i).
// k-loop unrolled x4 with float4 (ds_read_b128) A loads. In-place on d_out.
__global__ __launch_bounds__(256) void node_mlp_kernel(
    float* agg_out,
    const float* __restrict__ aggE,
    const float* __restrict__ degf,
    const float* __restrict__ We, const float* __restrict__ be,
    const float* __restrict__ W1, const float* __restrict__ b1,
    const float* __restrict__ W2, const float* __restrict__ b2,
    int N)
{
    __shared__ float sA[64][IN_F];
    __shared__ float sH[64][IN_F];
    const int t  = threadIdx.x;
    const int c4 = (t & 31) * 4;
    const int r0 = t >> 5;               // 0..7

    const int tile = blockIdx.x * 64;
    if (tile >= N) return;
    int rows = N - tile;
    if (rows > 64) rows = 64;

    // phase 1: a = agg + aggE@We + deg*be -> sA (8 rows/thread)
    {
        const float4 bev = *(const float4*)&be[c4];
        #pragma unroll
        for (int i = 0; i < 8; i++) {
            int rr = r0 + 8 * i;
            float4 v = make_float4(0.f, 0.f, 0.f, 0.f);
            if (rr < rows) {
                long long r = tile + rr;
                v = *(const float4*)&agg_out[r * IN_F + c4];
                float d = degf[r];
                v.x += d * bev.x; v.y += d * bev.y; v.z += d * bev.z; v.w += d * bev.w;
                #pragma unroll
                for (int k = 0; k < EF; k++) {
                    float a = aggE[r * EF + k];
                    float4 w = *(const float4*)&We[k * IN_F + c4];
                    v.x += a * w.x; v.y += a * w.y; v.z += a * w.z; v.w += a * w.w;
                }
            }
            *(float4*)&sA[rr][c4] = v;
        }
    }
    __syncthreads();

    // phase 2: h = relu(sA @ W1 + b1) -> sH
    {
        const float4 bv = *(const float4*)&b1[c4];
        float4 acc[8];
        #pragma unroll
        for (int i = 0; i < 8; i++) acc[i] = bv;
        for (int k = 0; k < IN_F; k += 4) {
            float4 w0 = *(const float4*)&W1[(k + 0) * IN_F + c4];
            float4 w1 = *(const float4*)&W1[(k + 1) * IN_F + c4];
            float4 w2 = *(const float4*)&W1[(k + 2) * IN_F + c4];
            float4 w3 = *(const float4*)&W1[(k + 3) * IN_F + c4];
            #pragma unroll
            for (int i = 0; i < 8; i++) {
                float4 x = *(const float4*)&sA[r0 + 8 * i][k];
                acc[i].x += x.x * w0.x + x.y * w1.x + x.z * w2.x + x.w * w3.x;
                acc[i].y += x.x * w0.y + x.y * w1.y + x.z * w2.y + x.w * w3.y;
                acc[i].z += x.x * w0.z + x.y * w1.z + x.z * w2.z + x.w * w3.z;
                acc[i].w += x.x * w0.w + x.y * w1.w + x.z * w2.w + x.w * w3.w;
            }
        }
        #pragma unroll
        for (int i = 0; i < 8; i++) {
            acc[i].x = fmaxf(acc[i].x, 0.f); acc[i].y = fmaxf(acc[i].y, 0.f);
            acc[i].z = fmaxf(acc[i].z, 0.f); acc[i].w = fmaxf(acc[i].w, 0.f);
            *(float4*)&sH[r0 + 8 * i][c4] = acc[i];
        }
    }
    __syncthreads();

    // phase 3: out = sH @ W2 + b2
    {
        const float4 bv = *(const float4*)&b2[c4];
        float4 acc[8];
        #pragma unroll
        for (int i = 0; i < 8; i++) acc[i] = bv;
        for (int k = 0; k < IN_F; k += 4) {
            float4 w0 = *(const float4*)&W2[(k + 0) * IN_F + c4];
            float4 w1 = *(const float4*)&W2[(k + 1) * IN_F + c4];
            float4 w2 = *(const float4*)&W2[(k + 2) * IN_F + c4];
            float4 w3 = *(const float4*)&W2[(k + 3) * IN_F + c4];
            #pragma unroll
            for (int i = 0; i < 8; i++) {
                float4 x = *(const float4*)&sH[r0 + 8 * i][k];
                acc[i].x += x.x * w0.x + x.y * w1.x + x.z * w2.x + x.w * w3.x;
                acc[i].y += x.x * w0.y + x.y * w1.y + x.z * w2.y + x.w * w3.y;
                acc[i].z += x.x * w0.z + x.y * w1.z + x.z * w2.z + x.w * w3.z;
                acc[i].w += x.x * w0.w + x.y * w1.w + x.z * w2.w + x.w * w3.w;
            }
        }
        #pragma unroll
        for (int i = 0; i < 8; i++) {
            int rr = r0 + 8 * i;
            if (rr < rows)
                *(float4*)&agg_out[(long long)(tile + rr) * IN_F + c4] = acc[i];
        }
    }
}

// ================================ host ======================================
extern "C" void kernel_launch(void* const* d_in, const int* in_sizes, int n_in,
                              void* d_out, int out_size, void* d_ws, size_t ws_size,
                              hipStream_t stream) {
    const float* H  = (const float*)d_in[0];
    const int*   ei = (const int*)d_in[1];     // int32 [2,E]
    const float* EA = (const float*)d_in[2];
    const float* We = (const float*)d_in[3];
    const float* be = (const float*)d_in[4];
    const float* W1 = (const float*)d_in[5];
    const float* b1 = (const float*)d_in[6];
    const float* W2 = (const float*)d_in[7];
    const float* b2 = (const float*)d_in[8];
    float* out = (float*)d_out;

    const int N = in_sizes[0] / IN_F;
    const int E = in_sizes[2] / EF;

    char* p = (char*)d_ws;
    auto alloc = [&](size_t bytes) { char* r = p; p += (bytes + 255) & ~(size_t)255; return r; };
    int2*  sorted   = (int2*)alloc((size_t)E * sizeof(int2));
    float* aggE     = (float*)alloc((size_t)N * EF * sizeof(float));
    float* degf     = (float*)alloc((size_t)N * sizeof(float));
    int*   counts   = (int*)alloc((size_t)(N + 1) * sizeof(int));
    int*   offsets  = (int*)alloc((size_t)(N + 1) * sizeof(int));
    int*   cursor   = (int*)alloc((size_t)N * sizeof(int));
    int*   partials = (int*)alloc(1024 * sizeof(int));
    size_t need_base = (size_t)(p - (char*)d_ws);
    unsigned short* Hb = (unsigned short*)alloc((size_t)N * IN_F * sizeof(unsigned short));
    size_t need_bf16 = (size_t)(p - (char*)d_ws);

    const int n_scan = N + 1;
    const int B = (n_scan + 1023) / 1024;

    if (ws_size >= need_base && B <= 1024) {
        hipMemsetAsync(counts, 0, (size_t)(N + 1) * sizeof(int), stream);
        hipMemsetAsync(cursor, 0, (size_t)N * sizeof(int), stream);
        hist_kernel<<<(E + 255) / 256, 256, 0, stream>>>(ei, counts, E);
        scan_blocks_kernel<<<B, 256, 0, stream>>>(counts, offsets, partials, n_scan);
        scan_partials_kernel<<<1, 1024, 0, stream>>>(partials, B);
        scan_add_kernel<<<(n_scan + 255) / 256, 256, 0, stream>>>(offsets, partials, n_scan);
        build_kernel<<<(E + 255) / 256, 256, 0, stream>>>(ei, sorted, offsets, cursor, E);
        if (ws_size >= need_bf16) {
            int n4 = N * IN_F / 4;
            h2b_kernel<<<(n4 + 255) / 256, 256, 0, stream>>>(H, Hb, n4);
            gather_bf16_kernel<<<(N + 3) / 4, 256, 0, stream>>>(Hb, EA, sorted, offsets, out, aggE, degf, N);
        } else {
            gather_f32_kernel<<<(N + 3) / 4, 256, 0, stream>>>(H, EA, sorted, offsets, out, aggE, degf, N);
        }
    } else {
        float* f_aggE = (float*)d_ws;
        float* f_deg  = f_aggE + (size_t)N * EF;
        aggE = f_aggE; degf = f_deg;
        hipMemsetAsync(d_out, 0, (size_t)N * IN_F * sizeof(float), stream);
        hipMemsetAsync(d_ws, 0, (size_t)N * (EF + 1) * sizeof(float), stream);
        long long tot = (long long)E * IN_F;
        edge_scatter_kernel<<<(int)((tot + 255) / 256), 256, 0, stream>>>(H, ei, EA, out, f_aggE, f_deg, E);
    }

    node_mlp_kernel<<<(N + 63) / 64, 256, 0, stream>>>(out, aggE, degf, We, be, W1, b1, W2, b2, N);
}

// Round 6
// 526.982 us; speedup vs baseline: 1.2274x; 1.2274x over previous
//
#include <hip/hip_runtime.h>

#define IN_F 128
#define EF 16

typedef short bf16x8 __attribute__((ext_vector_type(8)));
typedef float f32x4  __attribute__((ext_vector_type(4)));

// bf16 helpers: pack is RNE; unpack low/high halves of a uint holding 2 bf16
__device__ __forceinline__ unsigned short f2b(float f) {
    unsigned b = __float_as_uint(f);
    b += 0x7fffu + ((b >> 16) & 1u);
    return (unsigned short)(b >> 16);
}
__device__ __forceinline__ float blo(unsigned u) { return __uint_as_float(u << 16); }
__device__ __forceinline__ float bhi(unsigned u) { return __uint_as_float(u & 0xffff0000u); }

// ============================ CSR-build path ================================

__global__ __launch_bounds__(256) void hist_kernel(
    const int* __restrict__ ei, int* __restrict__ counts, int E)
{
    int e = blockIdx.x * 256 + threadIdx.x;
    if (e >= E) return;
    atomicAdd(&counts[ei[E + e]], 1);
}

__global__ __launch_bounds__(256) void scan_blocks_kernel(
    const int* __restrict__ in, int* __restrict__ out,
    int* __restrict__ partials, int n)
{
    __shared__ int sdata[256];
    const int t = threadIdx.x;
    const int idx0 = blockIdx.x * 1024 + t * 4;
    int v[4];
    #pragma unroll
    for (int i = 0; i < 4; i++) { int idx = idx0 + i; v[i] = (idx < n) ? in[idx] : 0; }
    int s = v[0] + v[1] + v[2] + v[3];
    sdata[t] = s;
    __syncthreads();
    for (int off = 1; off < 256; off <<= 1) {
        int x = (t >= off) ? sdata[t - off] : 0;
        __syncthreads();
        sdata[t] += x;
        __syncthreads();
    }
    if (t == 255) partials[blockIdx.x] = sdata[255];
    int run = (t > 0) ? sdata[t - 1] : 0;
    #pragma unroll
    for (int i = 0; i < 4; i++) {
        int idx = idx0 + i;
        if (idx < n) out[idx] = run;
        run += v[i];
    }
}

__global__ void scan_partials_kernel(int* partials, int B)
{
    __shared__ int sdata[1024];
    const int t = threadIdx.x;
    sdata[t] = (t < B) ? partials[t] : 0;
    __syncthreads();
    for (int off = 1; off < 1024; off <<= 1) {
        int x = (t >= off) ? sdata[t - off] : 0;
        __syncthreads();
        sdata[t] += x;
        __syncthreads();
    }
    if (t < B) partials[t] = (t > 0) ? sdata[t - 1] : 0;
}

__global__ __launch_bounds__(256) void scan_add_kernel(
    int* __restrict__ out, const int* __restrict__ partials, int n)
{
    int idx = blockIdx.x * 256 + threadIdx.x;
    if (idx < n) out[idx] += partials[idx >> 10];
}

__global__ __launch_bounds__(256) void build_kernel(
    const int* __restrict__ ei, int2* __restrict__ sorted,
    const int* __restrict__ offsets, int* __restrict__ cursor, int E)
{
    int e = blockIdx.x * 256 + threadIdx.x;
    if (e >= E) return;
    int src = ei[e];
    int dst = ei[E + e];
    int pos = offsets[dst] + atomicAdd(&cursor[dst], 1);
    sorted[pos] = make_int2(src, e);
}

// cast H (fp32) -> Hb (bf16, RNE), vectorized 4-wide
__global__ __launch_bounds__(256) void h2b_kernel(
    const float* __restrict__ H, unsigned short* __restrict__ Hb, int n4)
{
    int i = blockIdx.x * 256 + threadIdx.x;
    if (i >= n4) return;
    float4 v = ((const float4*)H)[i];
    ushort4 r;
    r.x = f2b(v.x); r.y = f2b(v.y); r.z = f2b(v.z); r.w = f2b(v.w);
    ((ushort4*)Hb)[i] = r;
}

// gather (bf16 H): one wave per node; half-waves each own one edge slot;
// lane covers feats [4*l32 .. 4*l32+3] via one 8B load. Unroll x4.
__global__ __launch_bounds__(256) void gather_bf16_kernel(
    const unsigned short* __restrict__ Hb,
    const float* __restrict__ EA,
    const int2* __restrict__ sorted,
    const int* __restrict__ offsets,
    float* __restrict__ agg,            // [N,128] = d_out
    float* __restrict__ aggE,           // [N,16]
    float* __restrict__ degf,           // [N]
    int N)
{
    int n = blockIdx.x * 4 + (threadIdx.x >> 6);
    if (n >= N) return;
    int lane = threadIdx.x & 63;
    int half = lane >> 5;
    int l32  = lane & 31;
    int s = offsets[n];
    int e_end = offsets[n + 1];
    float a0 = 0.f, a1 = 0.f, a2 = 0.f, a3 = 0.f, accE = 0.f;
    int i = s + half;
    for (; i + 6 < e_end; i += 8) {
        int2 s0 = sorted[i];
        int2 s1 = sorted[i + 2];
        int2 s2 = sorted[i + 4];
        int2 s3 = sorted[i + 6];
        uint2 u0 = *(const uint2*)(Hb + (long long)s0.x * IN_F + l32 * 4);
        uint2 u1 = *(const uint2*)(Hb + (long long)s1.x * IN_F + l32 * 4);
        uint2 u2 = *(const uint2*)(Hb + (long long)s2.x * IN_F + l32 * 4);
        uint2 u3 = *(const uint2*)(Hb + (long long)s3.x * IN_F + l32 * 4);
        float e0 = 0.f, e1 = 0.f, e2 = 0.f, e3 = 0.f;
        if (l32 < EF) {
            e0 = EA[(long long)s0.y * EF + l32];
            e1 = EA[(long long)s1.y * EF + l32];
            e2 = EA[(long long)s2.y * EF + l32];
            e3 = EA[(long long)s3.y * EF + l32];
        }
        a0 += (blo(u0.x) + blo(u1.x)) + (blo(u2.x) + blo(u3.x));
        a1 += (bhi(u0.x) + bhi(u1.x)) + (bhi(u2.x) + bhi(u3.x));
        a2 += (blo(u0.y) + blo(u1.y)) + (blo(u2.y) + blo(u3.y));
        a3 += (bhi(u0.y) + bhi(u1.y)) + (bhi(u2.y) + bhi(u3.y));
        accE += (e0 + e1) + (e2 + e3);
    }
    for (; i < e_end; i += 2) {
        int2 se = sorted[i];
        uint2 u = *(const uint2*)(Hb + (long long)se.x * IN_F + l32 * 4);
        a0 += blo(u.x); a1 += bhi(u.x); a2 += blo(u.y); a3 += bhi(u.y);
        if (l32 < EF) accE += EA[(long long)se.y * EF + l32];
    }
    a0 += __shfl_xor(a0, 32, 64);
    a1 += __shfl_xor(a1, 32, 64);
    a2 += __shfl_xor(a2, 32, 64);
    a3 += __shfl_xor(a3, 32, 64);
    accE += __shfl_xor(accE, 32, 64);
    if (half == 0) {
        *(float4*)(agg + (long long)n * IN_F + l32 * 4) = make_float4(a0, a1, a2, a3);
        if (l32 < EF) aggE[n * EF + l32] = accE;
        if (l32 == 0) degf[n] = (float)(e_end - s);
    }
}

// gather (fp32 H) fallback
__global__ __launch_bounds__(256) void gather_f32_kernel(
    const float* __restrict__ H,
    const float* __restrict__ EA,
    const int2* __restrict__ sorted,
    const int* __restrict__ offsets,
    float* __restrict__ agg,
    float* __restrict__ aggE,
    float* __restrict__ degf,
    int N)
{
    int n = blockIdx.x * 4 + (threadIdx.x >> 6);
    if (n >= N) return;
    int lane = threadIdx.x & 63;
    int half = lane >> 5;
    int l32  = lane & 31;
    int s = offsets[n];
    int e_end = offsets[n + 1];
    float4 acc = make_float4(0.f, 0.f, 0.f, 0.f);
    float accE = 0.f;
    int i = s + half;
    for (; i + 6 < e_end; i += 8) {
        int2 s0 = sorted[i];
        int2 s1 = sorted[i + 2];
        int2 s2 = sorted[i + 4];
        int2 s3 = sorted[i + 6];
        float4 v0 = *(const float4*)(H + (long long)s0.x * IN_F + l32 * 4);
        float4 v1 = *(const float4*)(H + (long long)s1.x * IN_F + l32 * 4);
        float4 v2 = *(const float4*)(H + (long long)s2.x * IN_F + l32 * 4);
        float4 v3 = *(const float4*)(H + (long long)s3.x * IN_F + l32 * 4);
        float e0 = 0.f, e1 = 0.f, e2 = 0.f, e3 = 0.f;
        if (l32 < EF) {
            e0 = EA[(long long)s0.y * EF + l32];
            e1 = EA[(long long)s1.y * EF + l32];
            e2 = EA[(long long)s2.y * EF + l32];
            e3 = EA[(long long)s3.y * EF + l32];
        }
        acc.x += (v0.x + v1.x) + (v2.x + v3.x);
        acc.y += (v0.y + v1.y) + (v2.y + v3.y);
        acc.z += (v0.z + v1.z) + (v2.z + v3.z);
        acc.w += (v0.w + v1.w) + (v2.w + v3.w);
        accE  += (e0 + e1) + (e2 + e3);
    }
    for (; i < e_end; i += 2) {
        int2 se = sorted[i];
        float4 v = *(const float4*)(H + (long long)se.x * IN_F + l32 * 4);
        acc.x += v.x; acc.y += v.y; acc.z += v.z; acc.w += v.w;
        if (l32 < EF) accE += EA[(long long)se.y * EF + l32];
    }
    acc.x += __shfl_xor(acc.x, 32, 64);
    acc.y += __shfl_xor(acc.y, 32, 64);
    acc.z += __shfl_xor(acc.z, 32, 64);
    acc.w += __shfl_xor(acc.w, 32, 64);
    accE  += __shfl_xor(accE, 32, 64);
    if (half == 0) {
        *(float4*)(agg + (long long)n * IN_F + l32 * 4) = acc;
        if (l32 < EF) aggE[n * EF + l32] = accE;
        if (l32 == 0) degf[n] = (float)(e_end - s);
    }
}

// ======================= fallback: atomic scatter ===========================
__global__ __launch_bounds__(256) void edge_scatter_kernel(
    const float* __restrict__ H,
    const int* __restrict__ ei,
    const float* __restrict__ EA,
    float* __restrict__ agg,
    float* __restrict__ aggE,
    float* __restrict__ deg,
    int E)
{
    long long gid = (long long)blockIdx.x * 256 + threadIdx.x;
    int e = (int)(gid >> 7);
    if (e >= E) return;
    int f = (int)(gid & 127);
    int src = ei[e];
    int dst = ei[E + e];
    float m = H[(long long)src * IN_F + f];
    atomicAdd(&agg[(long long)dst * IN_F + f], m);
    if (f < EF) atomicAdd(&aggE[dst * EF + f], EA[e * EF + f]);
    if (f == 0) atomicAdd(&deg[dst], 1.0f);
}

// ========================= MFMA node-MLP path ===============================

// prep: a = agg + aggE@We + deg*be  -> Ab (bf16 [N,128])
__global__ __launch_bounds__(256) void prep_kernel(
    const float* __restrict__ agg, const float* __restrict__ aggE,
    const float* __restrict__ degf,
    const float* __restrict__ We, const float* __restrict__ be,
    unsigned short* __restrict__ Ab, int N)
{
    int r = blockIdx.x * 8 + (threadIdx.x >> 5);
    if (r >= N) return;
    int c4 = (threadIdx.x & 31) * 4;
    float4 v = *(const float4*)&agg[(long long)r * IN_F + c4];
    float d = degf[r];
    float4 bev = *(const float4*)&be[c4];
    v.x += d * bev.x; v.y += d * bev.y; v.z += d * bev.z; v.w += d * bev.w;
    #pragma unroll
    for (int k = 0; k < EF; k++) {
        float a = aggE[r * EF + k];
        float4 w = *(const float4*)&We[k * IN_F + c4];
        v.x += a * w.x; v.y += a * w.y; v.z += a * w.z; v.w += a * w.w;
    }
    ushort4 o;
    o.x = f2b(v.x); o.y = f2b(v.y); o.z = f2b(v.z); o.w = f2b(v.w);
    *(ushort4*)&Ab[(long long)r * IN_F + c4] = o;
}

// transpose-cast W (fp32 [128][128], W[k][n]) -> Wt (bf16 [n][k])
__global__ __launch_bounds__(256) void wt_cast_kernel(
    const float* __restrict__ W, unsigned short* __restrict__ Wt)
{
    int idx = blockIdx.x * 256 + threadIdx.x;   // 16384 total
    int n = idx >> 7, k = idx & 127;
    Wt[n * IN_F + k] = f2b(W[k * IN_F + n]);
}

// fused 2-layer MLP on MFMA:
//   h = relu(Ab @ W1 + b1);  out = h @ W2 + b2
// 64-row tile, 4 waves; wave w owns rows M0=16w..M0+15. A-tile + Wt in LDS
// (pitch 136 shorts: row stride 68 dwords -> only free 2-way bank aliasing).
// h written back into the wave-private sX region (C/D -> A layout transform),
// W buffer barrier-swapped W1t -> W2t.
#define XPITCH 136
__global__ __launch_bounds__(256) void mlp_mfma_kernel(
    const unsigned short* __restrict__ Ab,
    const unsigned short* __restrict__ W1t,
    const unsigned short* __restrict__ W2t,
    const float* __restrict__ b1, const float* __restrict__ b2,
    float* __restrict__ out, int N)
{
    __shared__ unsigned short sW[128 * XPITCH];   // 34816 B
    __shared__ unsigned short sX[64 * XPITCH];    // 17408 B
    const int t    = threadIdx.x;
    const int tile = blockIdx.x * 64;
    const int lane = t & 63;
    const int wv   = t >> 6;          // 0..3
    const int quad = lane >> 4;       // 0..3
    const int lr   = lane & 15;
    const int M0   = wv * 16;

    // stage A tile (64 rows x 16 uint4) and W1t (128 rows x 16 uint4); 17 uint4/row pitch
    {
        const uint4 z = make_uint4(0, 0, 0, 0);
        #pragma unroll
        for (int j = 0; j < 4; j++) {
            int idx = t + 256 * j;                 // 0..1023
            int row = idx >> 4, c = idx & 15;
            uint4 v = z;
            if (tile + row < N) v = ((const uint4*)Ab)[(long long)(tile + row) * 16 + c];
            ((uint4*)sX)[row * 17 + c] = v;
        }
        #pragma unroll
        for (int j = 0; j < 8; j++) {
            int idx = t + 256 * j;                 // 0..2047
            int row = idx >> 4, c = idx & 15;
            ((uint4*)sW)[row * 17 + c] = ((const uint4*)W1t)[idx];
        }
    }
    __syncthreads();

    f32x4 acc[8];
    bf16x8 af[4];
    const f32x4 zero = {0.f, 0.f, 0.f, 0.f};

    // phase 2: h = relu(A @ W1 + b1) -> sX rows M0..M0+15 (wave-private)
    #pragma unroll
    for (int kt = 0; kt < 4; kt++)
        af[kt] = *(const bf16x8*)&sX[(M0 + lr) * XPITCH + kt * 32 + quad * 8];
    #pragma unroll
    for (int nt = 0; nt < 8; nt++) {
        acc[nt] = zero;
        #pragma unroll
        for (int kt = 0; kt < 4; kt++) {
            bf16x8 bf = *(const bf16x8*)&sW[(nt * 16 + lr) * XPITCH + kt * 32 + quad * 8];
            acc[nt] = __builtin_amdgcn_mfma_f32_16x16x32_bf16(af[kt], bf, acc[nt], 0, 0, 0);
        }
    }
    #pragma unroll
    for (int nt = 0; nt < 8; nt++) {
        int col = nt * 16 + lr;
        float bias = b1[col];
        #pragma unroll
        for (int r = 0; r < 4; r++) {
            float v = fmaxf(acc[nt][r] + bias, 0.f);
            sX[(M0 + quad * 4 + r) * XPITCH + col] = f2b(v);
        }
    }
    __syncthreads();    // all waves done reading W1t
    #pragma unroll
    for (int j = 0; j < 8; j++) {
        int idx = t + 256 * j;
        int row = idx >> 4, c = idx & 15;
        ((uint4*)sW)[row * 17 + c] = ((const uint4*)W2t)[idx];
    }
    __syncthreads();

    // phase 3: out = h @ W2 + b2
    #pragma unroll
    for (int kt = 0; kt < 4; kt++)
        af[kt] = *(const bf16x8*)&sX[(M0 + lr) * XPITCH + kt * 32 + quad * 8];
    #pragma unroll
    for (int nt = 0; nt < 8; nt++) {
        acc[nt] = zero;
        #pragma unroll
        for (int kt = 0; kt < 4; kt++) {
            bf16x8 bf = *(const bf16x8*)&sW[(nt * 16 + lr) * XPITCH + kt * 32 + quad * 8];
            acc[nt] = __builtin_amdgcn_mfma_f32_16x16x32_bf16(af[kt], bf, acc[nt], 0, 0, 0);
        }
    }
    #pragma unroll
    for (int nt = 0; nt < 8; nt++) {
        int col = nt * 16 + lr;
        float bias = b2[col];
        #pragma unroll
        for (int r = 0; r < 4; r++) {
            int row = tile + M0 + quad * 4 + r;
            if (row < N) out[(long long)row * IN_F + col] = acc[nt][r] + bias;
        }
    }
}

// ================== fp32 node MLP (fallback path only) ======================
__global__ __launch_bounds__(256) void node_mlp_kernel(
    float* agg_out,
    const float* __restrict__ aggE,
    const float* __restrict__ degf,
    const float* __restrict__ We, const float* __restrict__ be,
    const float* __restrict__ W1, const float* __restrict__ b1,
    const float* __restrict__ W2, const float* __restrict__ b2,
    int N)
{
    __shared__ float sA[32][IN_F];
    __shared__ float sH[32][IN_F];
    const int t  = threadIdx.x;
    const int c4 = (t & 31) * 4;
    const int r0 = t >> 5;

    const int tile = blockIdx.x * 32;
    if (tile >= N) return;
    int rows = N - tile;
    if (rows > 32) rows = 32;

    {
        const float4 bev = *(const float4*)&be[c4];
        #pragma unroll
        for (int i = 0; i < 4; i++) {
            int rr = r0 + 8 * i;
            float4 v = make_float4(0.f, 0.f, 0.f, 0.f);
            if (rr < rows) {
                long long r = tile + rr;
                v = *(const float4*)&agg_out[r * IN_F + c4];
                float d = degf[r];
                v.x += d * bev.x; v.y += d * bev.y; v.z += d * bev.z; v.w += d * bev.w;
                #pragma unroll
                for (int k = 0; k < EF; k++) {
                    float a = aggE[r * EF + k];
                    float4 w = *(const float4*)&We[k * IN_F + c4];
                    v.x += a * w.x; v.y += a * w.y; v.z += a * w.z; v.w += a * w.w;
                }
            }
            *(float4*)&sA[rr][c4] = v;
        }
    }
    __syncthreads();
    {
        const float4 bv = *(const float4*)&b1[c4];
        float4 a0 = bv, a1 = bv, a2 = bv, a3 = bv;
        for (int k = 0; k < IN_F; k++) {
            float4 w = *(const float4*)&W1[k * IN_F + c4];
            float x0 = sA[r0][k], x1 = sA[r0 + 8][k], x2 = sA[r0 + 16][k], x3 = sA[r0 + 24][k];
            a0.x += x0 * w.x; a0.y += x0 * w.y; a0.z += x0 * w.z; a0.w += x0 * w.w;
            a1.x += x1 * w.x; a1.y += x1 * w.y; a1.z += x1 * w.z; a1.w += x1 * w.w;
            a2.x += x2 * w.x; a2.y += x2 * w.y; a2.z += x2 * w.z; a2.w += x2 * w.w;
            a3.x += x3 * w.x; a3.y += x3 * w.y; a3.z += x3 * w.z; a3.w += x3 * w.w;
        }
        a0.x = fmaxf(a0.x, 0.f); a0.y = fmaxf(a0.y, 0.f); a0.z = fmaxf(a0.z, 0.f); a0.w = fmaxf(a0.w, 0.f);
        a1.x = fmaxf(a1.x, 0.f); a1.y = fmaxf(a1.y, 0.f); a1.z = fmaxf(a1.z, 0.f); a1.w = fmaxf(a1.w, 0.f);
        a2.x = fmaxf(a2.x, 0.f); a2.y = fmaxf(a2.y, 0.f); a2.z = fmaxf(a2.z, 0.f); a2.w = fmaxf(a2.w, 0.f);
        a3.x = fmaxf(a3.x, 0.f); a3.y = fmaxf(a3.y, 0.f); a3.z = fmaxf(a3.z, 0.f); a3.w = fmaxf(a3.w, 0.f);
        *(float4*)&sH[r0][c4]      = a0;
        *(float4*)&sH[r0 + 8][c4]  = a1;
        *(float4*)&sH[r0 + 16][c4] = a2;
        *(float4*)&sH[r0 + 24][c4] = a3;
    }
    __syncthreads();
    {
        const float4 bv = *(const float4*)&b2[c4];
        float4 a0 = bv, a1 = bv, a2 = bv, a3 = bv;
        for (int k = 0; k < IN_F; k++) {
            float4 w = *(const float4*)&W2[k * IN_F + c4];
            float x0 = sH[r0][k], x1 = sH[r0 + 8][k], x2 = sH[r0 + 16][k], x3 = sH[r0 + 24][k];
            a0.x += x0 * w.x; a0.y += x0 * w.y; a0.z += x0 * w.z; a0.w += x0 * w.w;
            a1.x += x1 * w.x; a1.y += x1 * w.y; a1.z += x1 * w.z; a1.w += x1 * w.w;
            a2.x += x2 * w.x; a2.y += x2 * w.y; a2.z += x2 * w.z; a2.w += x2 * w.w;
            a3.x += x3 * w.x; a3.y += x3 * w.y; a3.z += x3 * w.z; a3.w += x3 * w.w;
        }
        #pragma unroll
        for (int i = 0; i < 4; i++) {
            int rr = r0 + 8 * i;
            if (rr < rows) {
                float4 v = (i == 0) ? a0 : (i == 1) ? a1 : (i == 2) ? a2 : a3;
                *(float4*)&agg_out[(long long)(tile + rr) * IN_F + c4] = v;
            }
        }
    }
}

// ================================ host ======================================
extern "C" void kernel_launch(void* const* d_in, const int* in_sizes, int n_in,
                              void* d_out, int out_size, void* d_ws, size_t ws_size,
                              hipStream_t stream) {
    const float* H  = (const float*)d_in[0];
    const int*   ei = (const int*)d_in[1];     // int32 [2,E]
    const float* EA = (const float*)d_in[2];
    const float* We = (const float*)d_in[3];
    const float* be = (const float*)d_in[4];
    const float* W1 = (const float*)d_in[5];
    const float* b1 = (const float*)d_in[6];
    const float* W2 = (const float*)d_in[7];
    const float* b2 = (const float*)d_in[8];
    float* out = (float*)d_out;

    const int N = in_sizes[0] / IN_F;
    const int E = in_sizes[2] / EF;

    char* p = (char*)d_ws;
    auto alloc = [&](size_t bytes) { char* r = p; p += (bytes + 255) & ~(size_t)255; return r; };
    int2*  sorted   = (int2*)alloc((size_t)E * sizeof(int2));
    float* aggE     = (float*)alloc((size_t)N * EF * sizeof(float));
    float* degf     = (float*)alloc((size_t)N * sizeof(float));
    int*   counts   = (int*)alloc((size_t)(N + 1) * sizeof(int));
    int*   offsets  = (int*)alloc((size_t)(N + 1) * sizeof(int));
    int*   cursor   = (int*)alloc((size_t)N * sizeof(int));
    int*   partials = (int*)alloc(1024 * sizeof(int));
    size_t need_base = (size_t)(p - (char*)d_ws);
    unsigned short* Hb = (unsigned short*)alloc((size_t)N * IN_F * sizeof(unsigned short));
    size_t need_bf16 = (size_t)(p - (char*)d_ws);
    unsigned short* Ab  = (unsigned short*)alloc((size_t)N * IN_F * sizeof(unsigned short));
    unsigned short* W1t = (unsigned short*)alloc((size_t)IN_F * IN_F * sizeof(unsigned short));
    unsigned short* W2t = (unsigned short*)alloc((size_t)IN_F * IN_F * sizeof(unsigned short));
    size_t need_mfma = (size_t)(p - (char*)d_ws);

    const int n_scan = N + 1;
    const int B = (n_scan + 1023) / 1024;

    bool mfma_path = false;
    if (ws_size >= need_base && B <= 1024) {
        hipMemsetAsync(counts, 0, (size_t)(N + 1) * sizeof(int), stream);
        hipMemsetAsync(cursor, 0, (size_t)N * sizeof(int), stream);
        hist_kernel<<<(E + 255) / 256, 256, 0, stream>>>(ei, counts, E);
        scan_blocks_kernel<<<B, 256, 0, stream>>>(counts, offsets, partials, n_scan);
        scan_partials_kernel<<<1, 1024, 0, stream>>>(partials, B);
        scan_add_kernel<<<(n_scan + 255) / 256, 256, 0, stream>>>(offsets, partials, n_scan);
        build_kernel<<<(E + 255) / 256, 256, 0, stream>>>(ei, sorted, offsets, cursor, E);
        if (ws_size >= need_bf16) {
            int n4 = N * IN_F / 4;
            h2b_kernel<<<(n4 + 255) / 256, 256, 0, stream>>>(H, Hb, n4);
            gather_bf16_kernel<<<(N + 3) / 4, 256, 0, stream>>>(Hb, EA, sorted, offsets, out, aggE, degf, N);
        } else {
            gather_f32_kernel<<<(N + 3) / 4, 256, 0, stream>>>(H, EA, sorted, offsets, out, aggE, degf, N);
        }
        mfma_path = (ws_size >= need_mfma);
    } else {
        float* f_aggE = (float*)d_ws;
        float* f_deg  = f_aggE + (size_t)N * EF;
        aggE = f_aggE; degf = f_deg;
        hipMemsetAsync(d_out, 0, (size_t)N * IN_F * sizeof(float), stream);
        hipMemsetAsync(d_ws, 0, (size_t)N * (EF + 1) * sizeof(float), stream);
        long long tot = (long long)E * IN_F;
        edge_scatter_kernel<<<(int)((tot + 255) / 256), 256, 0, stream>>>(H, ei, EA, out, f_aggE, f_deg, E);
    }

    if (mfma_path) {
        wt_cast_kernel<<<64, 256, 0, stream>>>(W1, W1t);
        wt_cast_kernel<<<64, 256, 0, stream>>>(W2, W2t);
        prep_kernel<<<(N + 7) / 8, 256, 0, stream>>>(out, aggE, degf, We, be, Ab, N);
        mlp_mfma_kernel<<<(N + 63) / 64, 256, 0, stream>>>(Ab, W1t, W2t, b1, b2, out, N);
    } else {
        node_mlp_kernel<<<(N + 31) / 32, 256, 0, stream>>>(out, aggE, degf, We, be, W1, b1, W2, b2, N);
    }
}